// Round 1
// baseline (443.118 us; speedup 1.0000x reference)
//
#include <hip/hip_runtime.h>

// Problem constants: B=2, t=5, C=16, G=64
#define G3_    (64 * 64 * 64)          // 262144
#define CCH    16
#define TT     5
#define NPOSE  8
#define LSTRIDE 17                      // padded LDS x-stride
#define MAXZ   15                       // max bbox extent: 7*1.016*sqrt(3)+2 < 15
#define BUF    4096                     // floats: single LDS buffer (max idx 3822)

// ---------------------------------------------------------------------------
// Kernel 1: T = pose0 * inv(pose1); rigid -> inv([R|t]) = [R^T | -R^T t].
// ---------------------------------------------------------------------------
__global__ void pose_kernel(const float* __restrict__ cam, float* __restrict__ T)
{
    int n = threadIdx.x;
    if (n >= NPOSE) return;
    int b = n / (TT - 1);
    int j = n % (TT - 1);
    const float* p0 = cam + (size_t)(b * TT + 0) * 16;
    const float* p1 = cam + (size_t)(b * TT + j + 1) * 16;

    float R0[3][3], t0[3], R1[3][3], t1[3];
    #pragma unroll
    for (int r = 0; r < 3; ++r) {
        #pragma unroll
        for (int c = 0; c < 3; ++c) { R0[r][c] = p0[r * 4 + c]; R1[r][c] = p1[r * 4 + c]; }
        t0[r] = p0[r * 4 + 3];
        t1[r] = p1[r * 4 + 3];
    }
    float R[3][3], tr[3];
    #pragma unroll
    for (int r = 0; r < 3; ++r)
        #pragma unroll
        for (int c = 0; c < 3; ++c)
            R[r][c] = R0[r][0] * R1[c][0] + R0[r][1] * R1[c][1] + R0[r][2] * R1[c][2];
    #pragma unroll
    for (int r = 0; r < 3; ++r)
        tr[r] = t0[r] - (R[r][0] * t1[0] + R[r][1] * t1[1] + R[r][2] * t1[2]);

    float* o = T + n * 12;
    #pragma unroll
    for (int r = 0; r < 3; ++r) {
        #pragma unroll
        for (int c = 0; c < 3; ++c) o[r * 3 + c] = R[r][c];
        o[9 + r] = tr[r];
    }
}

// ---------------------------------------------------------------------------
// Kernel 2: out[:,0] = voxels[:,0], float4 copy.
// ---------------------------------------------------------------------------
__global__ __launch_bounds__(256) void copy0_kernel(const float* __restrict__ vox,
                                                    float* __restrict__ out)
{
    int tid = blockIdx.x * 256 + threadIdx.x;          // [0, 2^21)
    int b = tid >> 20;
    int r = tid & ((1 << 20) - 1);
    size_t base = (size_t)(b * TT) * CCH * G3_;
    const float4* s = (const float4*)(vox + base);
    float4* d = (float4*)(out + base);
    d[r] = s[r];
}

// ---------------------------------------------------------------------------
// Kernel 3: tiled trilinear warp, SINGLE 16 KB LDS buffer.
// Round-N change: the old 32 KB double buffer capped LDS residency at
// 5 blocks/CU and measured occupancy was 36% — the kernel was latency-bound
// (VALU 26%, HBM 24%, LDS ~50%: nothing saturated). Single buffer doubles
// the residency cap to 8 blocks/CU (wave-cap, 100%). The register pipeline
// is kept: channel c+1 global loads are issued before interpolating channel
// c, so HBM/L2 latency still hides behind interpolation; the c+1 registers
// are written to LDS only after a barrier confirms all reads of channel c
// are done, then a second barrier publishes them. The extra barrier per
// channel is covered by the extra resident blocks.
// Also removed: 32-float/thread LDS zero-init. All 8 corner reads are
// clamped into [0,s-1] per axis, which is exactly the staged index set, so
// padding/never-staged slots are provably never read.
// ---------------------------------------------------------------------------
__global__ __launch_bounds__(256, 8) void warp_kernel(const float* __restrict__ vox,
                                                      const float* __restrict__ T,
                                                      float* __restrict__ out)
{
    __shared__ float lds[BUF];                          // 16 KB
    const int tid = threadIdx.x;
    const int bid = blockIdx.x;
    const int n   = bid >> 9;                           // pose [0,8)
    const int t6  = bid & 511;
    const int ox  = (t6 & 7) << 3;
    const int oy  = ((t6 >> 3) & 7) << 3;
    const int oz  = (t6 >> 6) << 3;
    const int b   = n >> 2, j = n & 3;

    const float* Tn = T + n * 12;
    float R00 = Tn[0], R01 = Tn[1], R02 = Tn[2];
    float R10 = Tn[3], R11 = Tn[4], R12 = Tn[5];
    float R20 = Tn[6], R21 = Tn[7], R22 = Tn[8];
    float trx = Tn[9], try_ = Tn[10], trz = Tn[11];

    // ix = ax*gx + bx*gy + cx*gz + kx  (gx,gy,gz = output voxel index)
    const float S  = 1.0f / 64.0f;
    const float SC = 32.0f / 0.4921875f;
    const float ax = SC * R00 * S, bx = SC * R01 * S, cx = SC * R02 * S;
    const float ay = SC * R10 * S, by = SC * R11 * S, cy = SC * R12 * S;
    const float az = SC * R20 * S, bz = SC * R21 * S, cz = SC * R22 * S;
    const float kx = -31.5f * (ax + bx + cx) + SC * trx + 31.5f;
    const float ky = -31.5f * (ay + by + cy) + SC * try_ + 31.5f;
    const float kz = -31.5f * (az + bz + cz) + SC * trz + 31.5f;

    // bbox of sample coords over the tile (affine -> extrema at tile corners)
    float x0a = ax * ox, x0b = ax * (ox + 7);
    float x1a = bx * oy, x1b = bx * (oy + 7);
    float x2a = cx * oz, x2b = cx * (oz + 7);
    float min_ix = kx + fminf(x0a, x0b) + fminf(x1a, x1b) + fminf(x2a, x2b);
    float max_ix = kx + fmaxf(x0a, x0b) + fmaxf(x1a, x1b) + fmaxf(x2a, x2b);
    float y0a = ay * ox, y0b = ay * (ox + 7);
    float y1a = by * oy, y1b = by * (oy + 7);
    float y2a = cy * oz, y2b = cy * (oz + 7);
    float min_iy = ky + fminf(y0a, y0b) + fminf(y1a, y1b) + fminf(y2a, y2b);
    float max_iy = ky + fmaxf(y0a, y0b) + fmaxf(y1a, y1b) + fmaxf(y2a, y2b);
    float z0a = az * ox, z0b = az * (ox + 7);
    float z1a = bz * oy, z1b = bz * (oy + 7);
    float z2a = cz * oz, z2b = cz * (oz + 7);
    float min_iz = kz + fminf(z0a, z0b) + fminf(z1a, z1b) + fminf(z2a, z2b);
    float max_iz = kz + fmaxf(z0a, z0b) + fmaxf(z1a, z1b) + fmaxf(z2a, z2b);

    int xlo = min(max((int)floorf(min_ix), 0), 63);
    int xhi = min(max((int)floorf(max_ix) + 1, 0), 63);
    int ylo = min(max((int)floorf(min_iy), 0), 63);
    int yhi = min(max((int)floorf(max_iy) + 1, 0), 63);
    int zlo = min(max((int)floorf(min_iz), 0), 63);
    int zhi = min(max((int)floorf(max_iz) + 1, 0), 63);
    int sx = xhi - xlo + 1;     // <= 15
    int sy = yhi - ylo + 1;
    int sz = zhi - zlo + 1;
    const int lstep = sy * LSTRIDE;

    // per-thread precompute for 2 outputs: weights + independently-clamped
    // corner addresses (reference semantics).
    float w[2][6];
    int   ia[2][4], rxa[2][2], soff[2];
    #pragma unroll
    for (int k = 0; k < 2; ++k) {
        int o  = tid + (k << 8);
        int gx = ox + (o & 7);
        int gy = oy + ((o >> 3) & 7);
        int gz = oz + (o >> 6);
        float ix = kx + ax * gx + bx * gy + cx * gz;
        float iy = ky + ay * gx + by * gy + cy * gz;
        float iz = kz + az * gx + bz * gy + cz * gz;
        float fx = floorf(ix), fy = floorf(iy), fz = floorf(iz);
        float tx = ix - fx, ty = iy - fy, tz = iz - fz;
        int X0 = (int)fx, Y0 = (int)fy, Z0 = (int)fz;
        w[k][0] = ((unsigned)X0 < 64u) ? (1.0f - tx) : 0.0f;
        w[k][1] = ((unsigned)(X0 + 1) < 64u) ? tx : 0.0f;
        w[k][2] = ((unsigned)Y0 < 64u) ? (1.0f - ty) : 0.0f;
        w[k][3] = ((unsigned)(Y0 + 1) < 64u) ? ty : 0.0f;
        w[k][4] = ((unsigned)Z0 < 64u) ? (1.0f - tz) : 0.0f;
        w[k][5] = ((unsigned)(Z0 + 1) < 64u) ? tz : 0.0f;
        int rx0 = min(max(X0     - xlo, 0), sx - 1);
        int rx1 = min(max(X0 + 1 - xlo, 0), sx - 1);
        int ry0 = min(max(Y0     - ylo, 0), sy - 1) * LSTRIDE;
        int ry1 = min(max(Y0 + 1 - ylo, 0), sy - 1) * LSTRIDE;
        int rz0 = min(max(Z0     - zlo, 0), sz - 1) * lstep;
        int rz1 = min(max(Z0 + 1 - zlo, 0), sz - 1) * lstep;
        ia[k][0] = rz0 + ry0;
        ia[k][1] = rz0 + ry1;
        ia[k][2] = rz1 + ry0;
        ia[k][3] = rz1 + ry1;
        rxa[k][0] = rx0;
        rxa[k][1] = rx1;
        soff[k] = (gz << 12) + (gy << 6) + gx;
    }

    const size_t fb = (size_t)((b * TT + j + 1) * CCH) * G3_;
    const float* vbase = vox + fb;
    float* obase = out + fb;

    // staging assignment: 16 lanes cover x (row), 16 rows cover y; loop z.
    const int lane16 = tid & 15;
    const int row16  = tid >> 4;
    const bool act   = (lane16 < sx) && (row16 < sy);
    const int grow   = (zlo << 12) + ((ylo + row16) << 6) + xlo + lane16;
    const int lrow   = row16 * LSTRIDE + lane16;

    // prologue: stage channel 0 (latency exposed once per block)
    if (act) {
        const float* gp = vbase + grow;
        int la = lrow;
        for (int zz = 0; zz < sz; ++zz) {
            lds[la] = gp[(size_t)zz << 12];
            la += lstep;
        }
    }
    __syncthreads();

    for (int c = 0; c < CCH; ++c) {
        // (1) issue global loads for channel c+1 into registers — no wait.
        float stg[MAXZ];
        const bool pre = (c + 1 < CCH);
        if (pre && act) {
            const float* gp = vbase + (size_t)(c + 1) * G3_ + grow;
            #pragma unroll
            for (int zz = 0; zz < MAXZ; ++zz) {
                if (zz < sz) stg[zz] = gp[(size_t)zz << 12];   // sz is uniform
            }
        }

        // (2) interpolate channel c from the buffer (hides the load latency)
        const float* buf = lds;
        float* op = obase + (size_t)c * G3_;
        #pragma unroll
        for (int k = 0; k < 2; ++k) {
            int r0 = rxa[k][0], r1 = rxa[k][1];
            float v000 = buf[ia[k][0] + r0], v001 = buf[ia[k][0] + r1];
            float v010 = buf[ia[k][1] + r0], v011 = buf[ia[k][1] + r1];
            float v100 = buf[ia[k][2] + r0], v101 = buf[ia[k][2] + r1];
            float v110 = buf[ia[k][3] + r0], v111 = buf[ia[k][3] + r1];
            float t00 = v000 * w[k][0] + v001 * w[k][1];
            float t01 = v010 * w[k][0] + v011 * w[k][1];
            float t10 = v100 * w[k][0] + v101 * w[k][1];
            float t11 = v110 * w[k][2 - 2] * 0.0f + t01 * 0.0f + v110 * w[k][0] + v111 * w[k][1]; // placeholder removed below
            t11 = v110 * w[k][0] + v111 * w[k][1];
            float u0  = t00 * w[k][2] + t01 * w[k][3];
            float u1  = t10 * w[k][2] + t11 * w[k][3];
            op[soff[k]] = u0 * w[k][4] + u1 * w[k][5];
        }

        // (3) single-buffer handoff: barrier (all reads of channel c done),
        // write the landed c+1 registers, barrier (writes visible).
        if (pre) {
            __syncthreads();
            if (act) {
                #pragma unroll
                for (int zz = 0; zz < MAXZ; ++zz) {
                    if (zz < sz) lds[lrow + zz * lstep] = stg[zz];
                }
            }
            __syncthreads();
        }
    }
}

extern "C" void kernel_launch(void* const* d_in, const int* in_sizes, int n_in,
                              void* d_out, int out_size, void* d_ws, size_t ws_size,
                              hipStream_t stream)
{
    const float* vox = (const float*)d_in[0];
    const float* cam = (const float*)d_in[1];
    float* out = (float*)d_out;
    float* Tws = (float*)d_ws;   // 8 poses * 12 floats

    hipLaunchKernelGGL(pose_kernel, dim3(1), dim3(64), 0, stream, cam, Tws);
    hipLaunchKernelGGL(copy0_kernel, dim3(8192), dim3(256), 0, stream, vox, out);
    hipLaunchKernelGGL(warp_kernel, dim3(4096), dim3(256), 0, stream, vox, Tws, out);
}

// Round 2
// 398.899 us; speedup vs baseline: 1.1109x; 1.1109x over previous
//
#include <hip/hip_runtime.h>

// Problem constants: B=2, t=5, C=16, G=64
#define G3_    (64 * 64 * 64)          // 262144
#define CCH    16
#define TT     5
#define LSTRIDE 17                      // padded LDS x-stride (cols 0..16)
#define MAXZ   15                       // max bbox z extent
#define BUF    4096                     // floats per LDS buffer (max read idx 3841)
#define NWARP  4096
#define NCOPY  8192
#define NBLK   (NWARP + NCOPY)          // 12288 = 8 * 1536

// ---------------------------------------------------------------------------
// Single fused kernel.
//  - blocks with sbid%3==0 (4096): tiled trilinear warp of one 8^3 tile.
//  - blocks with sbid%3!=0 (8192): out[:,0] = voxels[:,0] float4 copy,
//    interleaved so the copy's 67 MB hides under the warp's spare HBM BW.
//  - pose T = pose0 * inv(pose1) computed redundantly per warp block
//    (rigid inverse, ~60 scalar FLOPs) -> no separate pose kernel / d_ws.
//  - XCD-contiguous swizzle: each XCD gets a contiguous sbid range so
//    x-adjacent tiles (overlapping staging bboxes) share L2.
//
// Warp-block changes vs previous round (163 us):
//  - interpolation reads the 8 corners as 4x ds_read2_b32: two z-bases,
//    constant dword offsets {0,1} (x-pair) and {17,18} (y-pair). Out-of-bbox
//    +1/+17 reads are weight-0 and land on staged-finite or zero-init slots.
//    The X0==-1 / Y0==-1 edge (low corner invalid, high valid) is handled by
//    swapping the axis weights once at setup instead of a 2nd clamped addr.
//  - staging loads even-aligned float2 x-pairs (xlo_e = xlo&~1, sxe<=16):
//    8-byte-aligned global loads, provably never out of the 64-float row;
//    LDS writes pair-merge to ds_write2_b32. 8 x-pairs x 16 rows, z split
//    across the two half-blocks (stg = 8 float2 = 16 VGPR).
//  - NO __launch_bounds__ min-waves (round-1 lesson: the reg cap spilled
//    stg/w to scratch: +183 MB HBM, VALU 13%).
// ---------------------------------------------------------------------------
__global__ __launch_bounds__(256) void fused_kernel(const float* __restrict__ vox,
                                                    const float* __restrict__ cam,
                                                    float* __restrict__ out)
{
    __shared__ float lds[2 * BUF];                      // 32 KB
    const int tid = threadIdx.x;

    // XCD-contiguous bijective swizzle (12288 % 8 == 0).
    const int bid  = blockIdx.x;
    const int sbid = (bid & 7) * (NBLK / 8) + (bid >> 3);
    const int w3   = sbid / 3;
    const int r3   = sbid - w3 * 3;

    if (r3 != 0) {
        // ---- copy block: out[:,0] = voxels[:,0] ----
        int cid = (w3 << 1) + (r3 - 1);                 // 0..8191
        int t4  = cid * 256 + tid;                      // [0, 2^21)
        int b   = t4 >> 20;
        int rr  = t4 & ((1 << 20) - 1);
        size_t base = (size_t)(b * TT) * CCH * G3_;
        const float4* s = (const float4*)(vox + base);
        float4* d = (float4*)(out + base);
        d[rr] = s[rr];
        return;
    }

    // ---- warp block ----
    const int n  = w3 >> 9;                             // pose [0,8)
    const int t6 = w3 & 511;
    const int ox = (t6 & 7) << 3;
    const int oy = ((t6 >> 3) & 7) << 3;
    const int oz = (t6 >> 6) << 3;
    const int b  = n >> 2, j = n & 3;

    // pose: T = P0 * inv(P1), rigid: R = R0*R1^T, tr = t0 - R*t1.
    const float* p0 = cam + (size_t)(b * TT) * 16;
    const float* p1 = cam + (size_t)(b * TT + j + 1) * 16;
    float a00 = p0[0], a01 = p0[1], a02 = p0[2],  at0 = p0[3];
    float a10 = p0[4], a11 = p0[5], a12 = p0[6],  at1 = p0[7];
    float a20 = p0[8], a21 = p0[9], a22 = p0[10], at2 = p0[11];
    float b00 = p1[0], b01 = p1[1], b02 = p1[2],  bt0 = p1[3];
    float b10 = p1[4], b11 = p1[5], b12 = p1[6],  bt1 = p1[7];
    float b20 = p1[8], b21 = p1[9], b22 = p1[10], bt2 = p1[11];
    float R00 = a00*b00 + a01*b01 + a02*b02;
    float R01 = a00*b10 + a01*b11 + a02*b12;
    float R02 = a00*b20 + a01*b21 + a02*b22;
    float R10 = a10*b00 + a11*b01 + a12*b02;
    float R11 = a10*b10 + a11*b11 + a12*b12;
    float R12 = a10*b20 + a11*b21 + a12*b22;
    float R20 = a20*b00 + a21*b01 + a22*b02;
    float R21 = a20*b10 + a21*b11 + a22*b12;
    float R22 = a20*b20 + a21*b21 + a22*b22;
    float trx = at0 - (R00*bt0 + R01*bt1 + R02*bt2);
    float try_= at1 - (R10*bt0 + R11*bt1 + R12*bt2);
    float trz = at2 - (R20*bt0 + R21*bt1 + R22*bt2);

    // ix = ax*gx + bx*gy + cx*gz + kx  (gx,gy,gz = output voxel index)
    const float S  = 1.0f / 64.0f;
    const float SC = 32.0f / 0.4921875f;
    const float ax = SC * R00 * S, bx = SC * R01 * S, cx = SC * R02 * S;
    const float ay = SC * R10 * S, by = SC * R11 * S, cy = SC * R12 * S;
    const float az = SC * R20 * S, bz = SC * R21 * S, cz = SC * R22 * S;
    const float kx = -31.5f * (ax + bx + cx) + SC * trx + 31.5f;
    const float ky = -31.5f * (ay + by + cy) + SC * try_ + 31.5f;
    const float kz = -31.5f * (az + bz + cz) + SC * trz + 31.5f;

    // bbox of sample coords over the tile (affine -> extrema at corners)
    float x0a = ax * ox, x0b = ax * (ox + 7);
    float x1a = bx * oy, x1b = bx * (oy + 7);
    float x2a = cx * oz, x2b = cx * (oz + 7);
    float min_ix = kx + fminf(x0a, x0b) + fminf(x1a, x1b) + fminf(x2a, x2b);
    float max_ix = kx + fmaxf(x0a, x0b) + fmaxf(x1a, x1b) + fmaxf(x2a, x2b);
    float y0a = ay * ox, y0b = ay * (ox + 7);
    float y1a = by * oy, y1b = by * (oy + 7);
    float y2a = cy * oz, y2b = cy * (oz + 7);
    float min_iy = ky + fminf(y0a, y0b) + fminf(y1a, y1b) + fminf(y2a, y2b);
    float max_iy = ky + fmaxf(y0a, y0b) + fmaxf(y1a, y1b) + fmaxf(y2a, y2b);
    float z0a = az * ox, z0b = az * (ox + 7);
    float z1a = bz * oy, z1b = bz * (oy + 7);
    float z2a = cz * oz, z2b = cz * (oz + 7);
    float min_iz = kz + fminf(z0a, z0b) + fminf(z1a, z1b) + fminf(z2a, z2b);
    float max_iz = kz + fmaxf(z0a, z0b) + fmaxf(z1a, z1b) + fmaxf(z2a, z2b);

    int xlo = min(max((int)floorf(min_ix), 0), 63);
    int xhi = min(max((int)floorf(max_ix) + 1, 0), 63);
    int ylo = min(max((int)floorf(min_iy), 0), 63);
    int yhi = min(max((int)floorf(max_iy) + 1, 0), 63);
    int zlo = min(max((int)floorf(min_iz), 0), 63);
    int zhi = min(max((int)floorf(max_iz) + 1, 0), 63);
    const int xlo_e = xlo & ~1;          // even-align for float2 staging
    const int sxe = xhi - xlo_e + 1;     // <= 16 (sx <= 15)
    const int sy  = yhi - ylo + 1;       // <= 15
    const int sz  = zhi - zlo + 1;       // <= 15
    const int lstep = sy * LSTRIDE;

    // per-thread interp setup (channel-invariant): weights with the
    // low-edge swap, two z-bases per output.
    float wx0[2], wx1[2], wy0[2], wy1[2], wz0[2], wz1[2];
    int base0[2], base1[2], soff[2];
    #pragma unroll
    for (int k = 0; k < 2; ++k) {
        int o  = tid + (k << 8);
        int gx = ox + (o & 7);
        int gy = oy + ((o >> 3) & 7);
        int gz = oz + (o >> 6);
        float ix = kx + ax * gx + bx * gy + cx * gz;
        float iy = ky + ay * gx + by * gy + cy * gz;
        float iz = kz + az * gx + bz * gy + cz * gz;
        float fx = floorf(ix), fy = floorf(iy), fz = floorf(iz);
        float tx = ix - fx, ty = iy - fy, tz = iz - fz;
        int X0 = (int)fx, Y0 = (int)fy, Z0 = (int)fz;

        float w0 = ((unsigned)X0 < 64u) ? (1.0f - tx) : 0.0f;
        float w1 = ((unsigned)(X0 + 1) < 64u) ? tx : 0.0f;
        int rxu = X0 - xlo_e;
        // X0==-1: low corner invalid, high valid at col 0 -> swap weights.
        wx0[k] = (rxu < 0) ? w1 : w0;
        wx1[k] = (rxu < 0) ? 0.0f : w1;
        int rx0 = min(max(rxu, 0), sxe - 1);

        w0 = ((unsigned)Y0 < 64u) ? (1.0f - ty) : 0.0f;
        w1 = ((unsigned)(Y0 + 1) < 64u) ? ty : 0.0f;
        int ryu = Y0 - ylo;
        wy0[k] = (ryu < 0) ? w1 : w0;
        wy1[k] = (ryu < 0) ? 0.0f : w1;
        int ry0 = min(max(ryu, 0), sy - 1);

        wz0[k] = ((unsigned)Z0 < 64u) ? (1.0f - tz) : 0.0f;
        wz1[k] = ((unsigned)(Z0 + 1) < 64u) ? tz : 0.0f;
        int rz0 = min(max(Z0     - zlo, 0), sz - 1);
        int rz1 = min(max(Z0 + 1 - zlo, 0), sz - 1);

        base0[k] = rz0 * lstep + ry0 * LSTRIDE + rx0;   // + {0,1,17,18}
        base1[k] = rz1 * lstep + ry0 * LSTRIDE + rx0;
        soff[k]  = (gz << 12) + (gy << 6) + gx;
    }

    const size_t fb = (size_t)((b * TT + j + 1) * CCH) * G3_;
    const float* vbase = vox + fb;
    float* obase = out + fb;

    // staging: 8 even x-pairs (float2) x 16 y-rows; z split across the
    // two half-blocks (zh). xe even <= 62 -> xe+1 <= 63: never leaves row.
    const int lane8 = tid & 7;
    const int row16 = (tid >> 3) & 15;
    const int zh    = tid >> 7;                         // 0/1
    const int xe    = xlo_e + (lane8 << 1);
    const bool actS = (xe <= xhi) && (row16 < sy);
    const int grow  = (zlo << 12) + ((ylo + row16) << 6) + xe;
    const int lrow  = row16 * LSTRIDE + (lane8 << 1);

    // zero-init both buffers (weight-0 reads of never-staged slots must be
    // finite/zero), then barrier BEFORE staging: cross-wave write race.
    #pragma unroll
    for (int i = 0; i < 32; ++i) lds[tid + i * 256] = 0.0f;
    __syncthreads();

    // prologue: stage channel 0 into buf0 (latency exposed once per block)
    if (actS) {
        const float2* gp = (const float2*)(vbase + grow);
        #pragma unroll
        for (int k = 0; k < 8; ++k) {
            int zz = (k << 1) + zh;
            if (zz < sz) {
                float2 v = gp[(size_t)zz << 11];
                float* wp = lds + lrow + zz * lstep;
                wp[0] = v.x;
                wp[1] = v.y;
            }
        }
    }
    __syncthreads();

    for (int c = 0; c < CCH; ++c) {
        // (1) issue global float2 loads for channel c+1 — no wait.
        float2 stg[8];
        const bool pre = (c + 1 < CCH);
        if (pre && actS) {
            const float2* gp = (const float2*)(vbase + (size_t)(c + 1) * G3_ + grow);
            #pragma unroll
            for (int k = 0; k < 8; ++k) {
                int zz = (k << 1) + zh;
                if (zz < sz) stg[k] = gp[(size_t)zz << 11];   // sz uniform
            }
        }

        // (2) interpolate channel c from buf[c&1]: 4x ds_read2_b32/output.
        const float* buf = lds + (c & 1) * BUF;
        float* op = obase + (size_t)c * G3_;
        #pragma unroll
        for (int k = 0; k < 2; ++k) {
            const float* pz0 = buf + base0[k];
            const float* pz1 = buf + base1[k];
            float v000 = pz0[0],  v001 = pz0[1];
            float v010 = pz0[17], v011 = pz0[18];
            float v100 = pz1[0],  v101 = pz1[1];
            float v110 = pz1[17], v111 = pz1[18];
            float t00 = v000 * wx0[k] + v001 * wx1[k];
            float t01 = v010 * wx0[k] + v011 * wx1[k];
            float t10 = v100 * wx0[k] + v101 * wx1[k];
            float t11 = v110 * wx0[k] + v111 * wx1[k];
            float u0  = t00 * wy0[k] + t01 * wy1[k];
            float u1  = t10 * wy0[k] + t11 * wy1[k];
            op[soff[k]] = u0 * wz0[k] + u1 * wz1[k];
        }

        // (3) write landed registers into buf[(c+1)&1]; safe: that buffer's
        // readers finished before the barrier at the end of iter c-1.
        if (pre) {
            float* wbuf = lds + ((c + 1) & 1) * BUF;
            if (actS) {
                #pragma unroll
                for (int k = 0; k < 8; ++k) {
                    int zz = (k << 1) + zh;
                    if (zz < sz) {
                        float* wp = wbuf + lrow + zz * lstep;
                        wp[0] = stg[k].x;
                        wp[1] = stg[k].y;
                    }
                }
            }
            __syncthreads();
        }
    }
}

extern "C" void kernel_launch(void* const* d_in, const int* in_sizes, int n_in,
                              void* d_out, int out_size, void* d_ws, size_t ws_size,
                              hipStream_t stream)
{
    const float* vox = (const float*)d_in[0];
    const float* cam = (const float*)d_in[1];
    float* out = (float*)d_out;
    (void)d_ws;

    hipLaunchKernelGGL(fused_kernel, dim3(NBLK), dim3(256), 0, stream, vox, cam, out);
}

// Round 3
// 357.741 us; speedup vs baseline: 1.2387x; 1.1150x over previous
//
#include <hip/hip_runtime.h>

// Problem constants: B=2, t=5, C=16, G=64
#define G3_    (64 * 64 * 64)          // 262144
#define CCH    16
#define TT     5
#define LSTRIDE 17                      // padded LDS x-stride (cols 0..16)
#define BUF    4096                     // floats: single LDS buffer (max read idx 3858)
#define NCHB   4                        // channels per warp block
#define NWARP  (4096 * (CCH / NCHB))    // 16384 warp blocks (tile x channel-group)
#define NCOPY  8192
#define NBLK   (NWARP + NCOPY)          // 24576 = 8 * 3072

// ---------------------------------------------------------------------------
// Single fused kernel, round-3 structure: CHANNEL-SPLIT x4, SINGLE 16KB BUF.
//
// Round-2 post-mortem: hbm_bytes (384 MB) is already ~algorithmic minimum,
// so the floor is ~64 us; we ran 198 us with VALU 16% / HBM 24% / occ 34%.
// Latency-bound: each block was a 16-channel serial chain of
// {loads -> interp -> vmcnt(0) -> ds_write -> barrier} with only ~2.7
// resident blocks/CU to cover the stalls. Fix parallelism structurally:
//  - each warp block = 4 channels of one 8^3 tile (16384 blocks, chain=4).
//    Channel-split duplicates only ~100 scalar setup ops; staging traffic
//    is NOT duplicated (each (tile,channel) staged exactly once).
//  - single 16 KB LDS buffer (two barriers per handoff) -> LDS cap 10
//    blocks/CU, wave-capped at 8 blocks = 100% occupancy potential.
//    Cross-block TLP now hides what the intra-block pipeline cannot.
//  - NO __launch_bounds__ min-waves (round-1 lesson: reg cap -> scratch
//    spill, +183 MB HBM).
// Kept from round 2: ds_read2_b32 corner reads (offsets {0,1},{17,18}) with
// low-edge weight swap; even-aligned float2 staging (merges to
// ds_write2_b32); redundant per-block pose; copy interleave; XCD swizzle.
// ---------------------------------------------------------------------------
__global__ __launch_bounds__(256) void fused_kernel(const float* __restrict__ vox,
                                                    const float* __restrict__ cam,
                                                    float* __restrict__ out)
{
    __shared__ float lds[BUF];                          // 16 KB
    const int tid = threadIdx.x;

    // XCD-contiguous bijective swizzle (24576 % 8 == 0).
    const int bid  = blockIdx.x;
    const int sbid = (bid & 7) * (NBLK / 8) + (bid >> 3);
    const int q3   = sbid / 3;
    const int r3   = sbid - q3 * 3;

    if (r3 == 2) {
        // ---- copy block: out[:,0] = voxels[:,0] ----
        int t4 = q3 * 256 + tid;                        // [0, 2^21)
        int b  = t4 >> 20;
        int rr = t4 & ((1 << 20) - 1);
        size_t base = (size_t)(b * TT) * CCH * G3_;
        const float4* s = (const float4*)(vox + base);
        float4* d = (float4*)(out + base);
        d[rr] = s[rr];
        return;
    }

    // ---- warp block: tile t9, channel group cg ----
    const int wid = q3 * 2 + r3;                        // [0, 16384)
    const int cg  = wid >> 12;                          // channel group [0,4)
    const int t9  = wid & 4095;                         // tile id
    const int n   = t9 >> 9;                            // pose [0,8)
    const int t6  = t9 & 511;
    const int ox  = (t6 & 7) << 3;
    const int oy  = ((t6 >> 3) & 7) << 3;
    const int oz  = (t6 >> 6) << 3;
    const int b   = n >> 2, j = n & 3;

    // pose: T = P0 * inv(P1), rigid: R = R0*R1^T, tr = t0 - R*t1.
    const float* p0 = cam + (size_t)(b * TT) * 16;
    const float* p1 = cam + (size_t)(b * TT + j + 1) * 16;
    float a00 = p0[0], a01 = p0[1], a02 = p0[2],  at0 = p0[3];
    float a10 = p0[4], a11 = p0[5], a12 = p0[6],  at1 = p0[7];
    float a20 = p0[8], a21 = p0[9], a22 = p0[10], at2 = p0[11];
    float b00 = p1[0], b01 = p1[1], b02 = p1[2],  bt0 = p1[3];
    float b10 = p1[4], b11 = p1[5], b12 = p1[6],  bt1 = p1[7];
    float b20 = p1[8], b21 = p1[9], b22 = p1[10], bt2 = p1[11];
    float R00 = a00*b00 + a01*b01 + a02*b02;
    float R01 = a00*b10 + a01*b11 + a02*b12;
    float R02 = a00*b20 + a01*b21 + a02*b22;
    float R10 = a10*b00 + a11*b01 + a12*b02;
    float R11 = a10*b10 + a11*b11 + a12*b12;
    float R12 = a10*b20 + a11*b21 + a12*b22;
    float R20 = a20*b00 + a21*b01 + a22*b02;
    float R21 = a20*b10 + a21*b11 + a22*b12;
    float R22 = a20*b20 + a21*b21 + a22*b22;
    float trx = at0 - (R00*bt0 + R01*bt1 + R02*bt2);
    float try_= at1 - (R10*bt0 + R11*bt1 + R12*bt2);
    float trz = at2 - (R20*bt0 + R21*bt1 + R22*bt2);

    // ix = ax*gx + bx*gy + cx*gz + kx  (gx,gy,gz = output voxel index)
    const float S  = 1.0f / 64.0f;
    const float SC = 32.0f / 0.4921875f;
    const float ax = SC * R00 * S, bx = SC * R01 * S, cx = SC * R02 * S;
    const float ay = SC * R10 * S, by = SC * R11 * S, cy = SC * R12 * S;
    const float az = SC * R20 * S, bz = SC * R21 * S, cz = SC * R22 * S;
    const float kx = -31.5f * (ax + bx + cx) + SC * trx + 31.5f;
    const float ky = -31.5f * (ay + by + cy) + SC * try_ + 31.5f;
    const float kz = -31.5f * (az + bz + cz) + SC * trz + 31.5f;

    // bbox of sample coords over the tile (affine -> extrema at corners)
    float x0a = ax * ox, x0b = ax * (ox + 7);
    float x1a = bx * oy, x1b = bx * (oy + 7);
    float x2a = cx * oz, x2b = cx * (oz + 7);
    float min_ix = kx + fminf(x0a, x0b) + fminf(x1a, x1b) + fminf(x2a, x2b);
    float max_ix = kx + fmaxf(x0a, x0b) + fmaxf(x1a, x1b) + fmaxf(x2a, x2b);
    float y0a = ay * ox, y0b = ay * (ox + 7);
    float y1a = by * oy, y1b = by * (oy + 7);
    float y2a = cy * oz, y2b = cy * (oz + 7);
    float min_iy = ky + fminf(y0a, y0b) + fminf(y1a, y1b) + fminf(y2a, y2b);
    float max_iy = ky + fmaxf(y0a, y0b) + fmaxf(y1a, y1b) + fmaxf(y2a, y2b);
    float z0a = az * ox, z0b = az * (ox + 7);
    float z1a = bz * oy, z1b = bz * (oy + 7);
    float z2a = cz * oz, z2b = cz * (oz + 7);
    float min_iz = kz + fminf(z0a, z0b) + fminf(z1a, z1b) + fminf(z2a, z2b);
    float max_iz = kz + fmaxf(z0a, z0b) + fmaxf(z1a, z1b) + fmaxf(z2a, z2b);

    int xlo = min(max((int)floorf(min_ix), 0), 63);
    int xhi = min(max((int)floorf(max_ix) + 1, 0), 63);
    int ylo = min(max((int)floorf(min_iy), 0), 63);
    int yhi = min(max((int)floorf(max_iy) + 1, 0), 63);
    int zlo = min(max((int)floorf(min_iz), 0), 63);
    int zhi = min(max((int)floorf(max_iz) + 1, 0), 63);
    const int xlo_e = xlo & ~1;          // even-align for float2 staging
    const int sxe = xhi - xlo_e + 1;     // <= 16 (sx <= 15)
    const int sy  = yhi - ylo + 1;       // <= 15
    const int sz  = zhi - zlo + 1;       // <= 15
    const int lstep = sy * LSTRIDE;

    // per-thread interp setup (channel-invariant): weights with the
    // low-edge swap, two z-bases per output.
    float wx0[2], wx1[2], wy0[2], wy1[2], wz0[2], wz1[2];
    int base0[2], base1[2], soff[2];
    #pragma unroll
    for (int k = 0; k < 2; ++k) {
        int o  = tid + (k << 8);
        int gx = ox + (o & 7);
        int gy = oy + ((o >> 3) & 7);
        int gz = oz + (o >> 6);
        float ix = kx + ax * gx + bx * gy + cx * gz;
        float iy = ky + ay * gx + by * gy + cy * gz;
        float iz = kz + az * gx + bz * gy + cz * gz;
        float fx = floorf(ix), fy = floorf(iy), fz = floorf(iz);
        float tx = ix - fx, ty = iy - fy, tz = iz - fz;
        int X0 = (int)fx, Y0 = (int)fy, Z0 = (int)fz;

        float w0 = ((unsigned)X0 < 64u) ? (1.0f - tx) : 0.0f;
        float w1 = ((unsigned)(X0 + 1) < 64u) ? tx : 0.0f;
        int rxu = X0 - xlo_e;
        // X0==-1: low corner invalid, high valid at col 0 -> swap weights.
        wx0[k] = (rxu < 0) ? w1 : w0;
        wx1[k] = (rxu < 0) ? 0.0f : w1;
        int rx0 = min(max(rxu, 0), sxe - 1);

        w0 = ((unsigned)Y0 < 64u) ? (1.0f - ty) : 0.0f;
        w1 = ((unsigned)(Y0 + 1) < 64u) ? ty : 0.0f;
        int ryu = Y0 - ylo;
        wy0[k] = (ryu < 0) ? w1 : w0;
        wy1[k] = (ryu < 0) ? 0.0f : w1;
        int ry0 = min(max(ryu, 0), sy - 1);

        wz0[k] = ((unsigned)Z0 < 64u) ? (1.0f - tz) : 0.0f;
        wz1[k] = ((unsigned)(Z0 + 1) < 64u) ? tz : 0.0f;
        int rz0 = min(max(Z0     - zlo, 0), sz - 1);
        int rz1 = min(max(Z0 + 1 - zlo, 0), sz - 1);

        base0[k] = rz0 * lstep + ry0 * LSTRIDE + rx0;   // + {0,1,17,18}
        base1[k] = rz1 * lstep + ry0 * LSTRIDE + rx0;
        soff[k]  = (gz << 12) + (gy << 6) + gx;
    }

    // channel-group base: channels [cg*NCHB, cg*NCHB + NCHB)
    const size_t fb = ((size_t)(b * TT + j + 1) * CCH + cg * NCHB) * G3_;
    const float* vbase = vox + fb;
    float* obase = out + fb;

    // staging: 8 even x-pairs (float2) x 16 y-rows; z split across the
    // two half-blocks (zh). xe even <= 62 -> xe+1 <= 63: never leaves row.
    const int lane8 = tid & 7;
    const int row16 = (tid >> 3) & 15;
    const int zh    = tid >> 7;                         // 0/1
    const int xe    = xlo_e + (lane8 << 1);
    const bool actS = (xe <= xhi) && (row16 < sy);
    const int grow  = (zlo << 12) + ((ylo + row16) << 6) + xe;
    const int lrow  = row16 * LSTRIDE + (lane8 << 1);

    float2 stg[8];

    // prologue: issue channel-0 loads FIRST (latency hides under the
    // zero-init + barrier), zero-init the buffer (weight-0 reads of
    // never-staged slots must be finite), barrier, write, barrier.
    if (actS) {
        const float2* gp = (const float2*)(vbase + grow);
        #pragma unroll
        for (int k = 0; k < 8; ++k) {
            int zz = (k << 1) + zh;
            if (zz < sz) stg[k] = gp[(size_t)zz << 11];
        }
    }
    #pragma unroll
    for (int i = 0; i < 16; ++i) lds[tid + i * 256] = 0.0f;
    __syncthreads();
    if (actS) {
        #pragma unroll
        for (int k = 0; k < 8; ++k) {
            int zz = (k << 1) + zh;
            if (zz < sz) {
                float* wp = lds + lrow + zz * lstep;
                wp[0] = stg[k].x;
                wp[1] = stg[k].y;
            }
        }
    }
    __syncthreads();

    for (int cc = 0; cc < NCHB; ++cc) {
        // (1) issue global float2 loads for channel cc+1 — no wait.
        const bool pre = (cc + 1 < NCHB);
        if (pre && actS) {
            const float2* gp = (const float2*)(vbase + (size_t)(cc + 1) * G3_ + grow);
            #pragma unroll
            for (int k = 0; k < 8; ++k) {
                int zz = (k << 1) + zh;
                if (zz < sz) stg[k] = gp[(size_t)zz << 11];   // sz uniform
            }
        }

        // (2) interpolate channel cc: 4x ds_read2_b32 per output.
        float* op = obase + (size_t)cc * G3_;
        #pragma unroll
        for (int k = 0; k < 2; ++k) {
            const float* pz0 = lds + base0[k];
            const float* pz1 = lds + base1[k];
            float v000 = pz0[0],  v001 = pz0[1];
            float v010 = pz0[17], v011 = pz0[18];
            float v100 = pz1[0],  v101 = pz1[1];
            float v110 = pz1[17], v111 = pz1[18];
            float t00 = v000 * wx0[k] + v001 * wx1[k];
            float t01 = v010 * wx0[k] + v011 * wx1[k];
            float t10 = v100 * wx0[k] + v101 * wx1[k];
            float t11 = v110 * wx0[k] + v111 * wx1[k];
            float u0  = t00 * wy0[k] + t01 * wy1[k];
            float u1  = t10 * wy0[k] + t11 * wy1[k];
            op[soff[k]] = u0 * wz0[k] + u1 * wz1[k];
        }

        // (3) single-buffer handoff: barrier (reads of cc done), write the
        // landed cc+1 registers, barrier (writes visible). Cross-block TLP
        // (up to 8 resident blocks/CU) covers these stalls.
        if (pre) {
            __syncthreads();
            if (actS) {
                #pragma unroll
                for (int k = 0; k < 8; ++k) {
                    int zz = (k << 1) + zh;
                    if (zz < sz) {
                        float* wp = lds + lrow + zz * lstep;
                        wp[0] = stg[k].x;
                        wp[1] = stg[k].y;
                    }
                }
            }
            __syncthreads();
        }
    }
}

extern "C" void kernel_launch(void* const* d_in, const int* in_sizes, int n_in,
                              void* d_out, int out_size, void* d_ws, size_t ws_size,
                              hipStream_t stream)
{
    const float* vox = (const float*)d_in[0];
    const float* cam = (const float*)d_in[1];
    float* out = (float*)d_out;
    (void)d_ws;

    hipLaunchKernelGGL(fused_kernel, dim3(NBLK), dim3(256), 0, stream, vox, cam, out);
}